// Round 1
// baseline (155.980 us; speedup 1.0000x reference)
//
#include <hip/hip_runtime.h>

// Occlusion kernel: out = (1/NUM_GRAPHS) * sum_e exp(-||pos[dst_e] - pos[src_e]||)
// batch_idx is irrelevant: all segment ids are in range, and we take the mean
// over ALL segments, so segment_sum followed by mean == total_sum / NUM_GRAPHS.

#define N_EDGES_C 8388608
#define INV_NUM_GRAPHS (1.0f / 1024.0f)

__global__ __launch_bounds__(256) void occlusion_reduce(
    const float2* __restrict__ pos,   // [N_NODES] (x, y)
    const int*    __restrict__ src,   // [E] edge sources   (edge_index row 0)
    const int*    __restrict__ dst,   // [E] edge dests     (edge_index row 1)
    float*        __restrict__ out)   // [1] result
{
    const int tid    = blockIdx.x * blockDim.x + threadIdx.x;
    const int stride = gridDim.x * blockDim.x;

    const int4* __restrict__ src4 = reinterpret_cast<const int4*>(src);
    const int4* __restrict__ dst4 = reinterpret_cast<const int4*>(dst);
    const int n4 = N_EDGES_C / 4;

    float acc = 0.0f;
    for (int i = tid; i < n4; i += stride) {
        const int4 s = src4[i];
        const int4 d = dst4[i];

        float2 ps, pd;
        float dx, dy;

        ps = pos[s.x]; pd = pos[d.x];
        dx = pd.x - ps.x; dy = pd.y - ps.y;
        acc += __expf(-sqrtf(dx * dx + dy * dy));

        ps = pos[s.y]; pd = pos[d.y];
        dx = pd.x - ps.x; dy = pd.y - ps.y;
        acc += __expf(-sqrtf(dx * dx + dy * dy));

        ps = pos[s.z]; pd = pos[d.z];
        dx = pd.x - ps.x; dy = pd.y - ps.y;
        acc += __expf(-sqrtf(dx * dx + dy * dy));

        ps = pos[s.w]; pd = pos[d.w];
        dx = pd.x - ps.x; dy = pd.y - ps.y;
        acc += __expf(-sqrtf(dx * dx + dy * dy));
    }

    // wave-64 butterfly reduce
    #pragma unroll
    for (int off = 32; off > 0; off >>= 1)
        acc += __shfl_down(acc, off, 64);

    __shared__ float wave_sums[4];  // 256 threads = 4 waves
    const int lane = threadIdx.x & 63;
    const int wid  = threadIdx.x >> 6;
    if (lane == 0) wave_sums[wid] = acc;
    __syncthreads();

    if (threadIdx.x == 0) {
        float s = wave_sums[0] + wave_sums[1] + wave_sums[2] + wave_sums[3];
        atomicAdd(out, s * INV_NUM_GRAPHS);
    }
}

extern "C" void kernel_launch(void* const* d_in, const int* in_sizes, int n_in,
                              void* d_out, int out_size, void* d_ws, size_t ws_size,
                              hipStream_t stream) {
    const float* node_pos = (const float*)d_in[0];        // [N_NODES, 2] f32
    const int*   edge_idx = (const int*)d_in[1];          // [2, E] int32 (JAX x64 off)
    // d_in[2] = batch_idx — unused (see header comment)

    const int E = in_sizes[1] / 2;                        // 8388608
    const int* src = edge_idx;
    const int* dst = edge_idx + E;

    float* out = (float*)d_out;
    // harness poisons d_out with 0xAA before every timed replay — zero it (capture-safe async memset)
    hipMemsetAsync(out, 0, sizeof(float), stream);

    const int block = 256;
    const int grid  = 2048;  // 524288 threads, 4 int4-edges-groups each; grid-stride covers E/4
    occlusion_reduce<<<grid, block, 0, stream>>>(
        reinterpret_cast<const float2*>(node_pos), src, dst, out);
}